// Round 8
// baseline (194.585 us; speedup 1.0000x reference)
//
#include <hip/hip_runtime.h>
#include <stdint.h>

typedef __bf16 bf16;
typedef __attribute__((ext_vector_type(8))) __bf16 bf16x8;
typedef __attribute__((ext_vector_type(4))) __bf16 bf16x4;
typedef __attribute__((ext_vector_type(4))) float f32x4;
typedef __attribute__((ext_vector_type(16))) float f32x16;
typedef __attribute__((ext_vector_type(4))) unsigned short us4;

constexpr int B_   = 2;
constexpr int T_   = 2048;
constexpr int DIM_ = 2048;
constexpr int H_   = 32;
constexpr int KVH_ = 8;
constexpr int HD_  = 64;
constexpr int BT_ROWS = B_ * T_;            // 4096
constexpr int NQKV = H_*HD_ + 2*KVH_*HD_;   // 3072
constexpr int KOFF = H_*HD_;                // 2048
constexpr int VOFF = H_*HD_ + KVH_*HD_;     // 2560

#define DEV __device__ __forceinline__

DEV void gload16(const void* g, void* l) {
  __builtin_amdgcn_global_load_lds((const __attribute__((address_space(1))) void*)g,
                                   (__attribute__((address_space(3))) void*)l,
                                   16, 0, 0);
}

// ---------------- fused prep: x cvt + 4x weight transpose + RoPE table transpose ----------------
__global__ void prep_kernel(const float* __restrict__ x,
                            const float* __restrict__ wq, const float* __restrict__ wk,
                            const float* __restrict__ wv, const float* __restrict__ wo,
                            const float* __restrict__ fc, const float* __restrict__ fs,
                            bf16* __restrict__ xb, bf16* __restrict__ wT,
                            bf16* __restrict__ woT,
                            float* __restrict__ fcT, float* __restrict__ fsT) {
  const int id = blockIdx.x;
  const int tid = threadIdx.y * 32 + threadIdx.x;
  if (id < 8192) {
    int gid = id * 256 + tid;
    float4 f = ((const float4*)x)[gid];
    bf16x4 o;
    o[0] = (bf16)f.x; o[1] = (bf16)f.y; o[2] = (bf16)f.z; o[3] = (bf16)f.w;
    ((bf16x4*)xb)[gid] = o;
    return;
  }
  __shared__ float tile[32][33];
  int td = id - 8192;
  int tx = threadIdx.x, ty = threadIdx.y;
  if (td < 10240) {
    const float* in; bf16* out; int C, bid;
    if (td < 4096)      { in = wq; out = wT;               C = 2048; bid = td; }
    else if (td < 5120) { in = wk; out = wT + 2048*2048;   C = 512;  bid = td - 4096; }
    else if (td < 6144) { in = wv; out = wT + 2560*2048;   C = 512;  bid = td - 5120; }
    else                { in = wo; out = woT;              C = 2048; bid = td - 6144; }
    const int R = 2048;
    int ct = C / 32;
    int bx = bid % ct, by = bid / ct;
#pragma unroll
    for (int i = ty; i < 32; i += 8)
      tile[i][tx] = in[(by*32 + i) * C + bx*32 + tx];
    __syncthreads();
#pragma unroll
    for (int i = ty; i < 32; i += 8)
      out[(bx*32 + i) * R + by*32 + tx] = (bf16)tile[tx][i];
  } else {
    // RoPE table transpose: [2048][32] f32 -> [32][2048] f32
    int tt = td - 10240;                  // [0,128)
    const float* in = (tt >= 64) ? fs : fc;
    float* outf = (tt >= 64) ? fsT : fcT;
    int bid = tt & 63;                    // t-tile index
#pragma unroll
    for (int i = ty; i < 32; i += 8)
      tile[i][tx] = in[(bid*32 + i) * 32 + tx];
    __syncthreads();
#pragma unroll
    for (int i = ty; i < 32; i += 8)
      outf[i * 2048 + bid*32 + tx] = tile[tx][i];
  }
}

// ---------------- GEMM: C[M,N] = A[M,K] * B[K,N], B given transposed (N,K) ----------------
// 128x128 tile, BK=64, 4 waves, single-buffer 2-barrier, 32x32x16 MFMA.
// MODE 0: plain f32 C store (out-proj), (256,2). MODE 1: qkv fused epilogue
// (RoPE via adjacent-lane shfl + transposed tables; V written as V^T), (256,3).
// MODE 1 folds the attention softmax scale (0.125*log2e) into the Q region.
template<int MODE>
__global__ __launch_bounds__(256, MODE == 1 ? 3 : 2)
void gemm_bt(const bf16* __restrict__ A, const bf16* __restrict__ BTm,
             void* __restrict__ Cv, int M, int N, int K,
             const float* __restrict__ fcT, const float* __restrict__ fsT,
             bf16* __restrict__ vt) {
  __shared__ __align__(16) bf16 As[128 * 64];
  __shared__ __align__(16) bf16 Bs[128 * 64];
  const int nbn = N >> 7;
  const int bm = blockIdx.x / nbn, bn = blockIdx.x % nbn;
  const int tid = threadIdx.x;
  const int w = tid >> 6, l = tid & 63;
  const int wr = w >> 1, wc = w & 1;
  const int lr = l & 31;              // row/col within 32x32 fragment
  const int hi = l >> 5;              // k-chunk select (0/1)
  const int crow = l >> 3;            // staging: row within 8-row group
  const int cch  = (l & 7) ^ crow;    // staging: inverse-swizzled source chunk

  f32x16 acc[2][2];
#pragma unroll
  for (int i = 0; i < 2; ++i)
#pragma unroll
    for (int j = 0; j < 2; ++j) acc[i][j] = 0.f;

  const bf16* ap[4];
  const bf16* bp[4];
#pragma unroll
  for (int i = 0; i < 4; ++i) {
    int row = (w*4 + i) * 8 + crow;
    ap[i] = A   + (long)(bm*128 + row) * K + cch*8;
    bp[i] = BTm + (long)(bn*128 + row) * K + cch*8;
  }
  int aoff[4][2], boff[4][2];
#pragma unroll
  for (int ks = 0; ks < 4; ++ks)
#pragma unroll
    for (int i = 0; i < 2; ++i) {
      int arow = wr*64 + i*32 + lr;
      int brow = wc*64 + i*32 + lr;
      aoff[ks][i] = arow*64 + (((2*ks + hi) ^ (arow & 7)) << 3);
      boff[ks][i] = brow*64 + (((2*ks + hi) ^ (brow & 7)) << 3);
    }

  for (int k0 = 0; k0 < K; k0 += 64) {
#pragma unroll
    for (int i = 0; i < 4; ++i) {
      gload16(ap[i], &As[(w*4 + i) * 512]);
      gload16(bp[i], &Bs[(w*4 + i) * 512]);
      ap[i] += 64; bp[i] += 64;
    }
    __syncthreads();
#pragma unroll
    for (int ks = 0; ks < 4; ++ks) {
      bf16x8 af[2], bfr[2];
#pragma unroll
      for (int i = 0; i < 2; ++i) af[i]  = *(const bf16x8*)&As[aoff[ks][i]];
#pragma unroll
      for (int j = 0; j < 2; ++j) bfr[j] = *(const bf16x8*)&Bs[boff[ks][j]];
#pragma unroll
      for (int i = 0; i < 2; ++i)
#pragma unroll
        for (int j = 0; j < 2; ++j)
          acc[i][j] = __builtin_amdgcn_mfma_f32_32x32x16_bf16(af[i], bfr[j], acc[i][j], 0, 0, 0);
    }
    __syncthreads();
  }

  // epilogue: C/D layout col = l&31, row = (reg&3) + 8*(reg>>2) + 4*(l>>5)
  const int row0 = bm*128 + wr*64, col0 = bn*128 + wc*64;
  if (MODE == 0) {
#pragma unroll
    for (int i = 0; i < 2; ++i)
#pragma unroll
      for (int j = 0; j < 2; ++j)
#pragma unroll
        for (int reg = 0; reg < 16; ++reg) {
          int rr = row0 + i*32 + (reg & 3) + 8*(reg >> 2) + 4*hi;
          int cc = col0 + j*32 + lr;
          ((float*)Cv)[(long)rr * N + cc] = acc[i][j][reg];
        }
  } else {
    if (col0 < VOFF) {
      // RoPE (q and k regions): pair = adjacent lanes; tables transposed -> float4 t-runs
      const float sgn = (lr & 1) ? 1.f : -1.f;
#pragma unroll
      for (int i = 0; i < 2; ++i) {
        const int tb0 = ((row0 + i*32) & (T_ - 1)) + 4*hi;
#pragma unroll
        for (int j = 0; j < 2; ++j) {
          const int cc = col0 + j*32 + lr;
          // fold softmax scale*log2(e) into Q (q region only)
          const float qsc = (col0 + j*32 < KOFF) ? 0.18033688f : 1.0f;
          const int p0 = (cc & 63) >> 1;
          const float* fct = fcT + p0*2048 + tb0;
          const float* fst = fsT + p0*2048 + tb0;
#pragma unroll
          for (int q = 0; q < 4; ++q) {
            float4 c4 = *(const float4*)(fct + 8*q);
            float4 s4 = *(const float4*)(fst + 8*q);
#pragma unroll
            for (int r = 0; r < 4; ++r) {
              float v = acc[i][j][q*4 + r];
              float other = __shfl_xor(v, 1);
              float cse = (&c4.x)[r], sse = (&s4.x)[r];
              float out = fmaf(sgn * other, sse, v * cse) * qsc;
              const int rr = row0 + i*32 + r + 8*q + 4*hi;
              ((bf16*)Cv)[(long)rr * N + cc] = (bf16)out;
            }
          }
        }
      }
    } else {
      // V region: write V^T directly (t-contiguous 4-packs)
      const int bglob = row0 >> 11;
#pragma unroll
      for (int i = 0; i < 2; ++i)
#pragma unroll
        for (int j = 0; j < 2; ++j) {
          const int vo = col0 + j*32 + lr - VOFF;
          const long vbase = (long)((bglob*KVH_ + (vo >> 6))*HD_ + (vo & 63)) * T_;
#pragma unroll
          for (int q = 0; q < 4; ++q) {
            bf16x4 pk;
#pragma unroll
            for (int r = 0; r < 4; ++r) pk[r] = (bf16)acc[i][j][q*4 + r];
            const int t = ((row0 + i*32) & (T_ - 1)) + 8*q + 4*hi;
            *(bf16x4*)&vt[vbase + t] = pk;
          }
        }
    }
  }
}

// ---------------- GQA causal flash attention ----------------
// 1024 blocks x 256 threads (4 waves), ONE q-tile (128 rows) per block,
// each wave owns 32 q-rows as TWO 16-row fragments (K/V LDS reads shared).
// THIS ROUND (T15 finish-lag pipeline): in iteration kt the wave issues
// PV(kt-1) (carried in-register pa fragments, V[(kt-1)%3]) back-to-back with
// QK(kt) -- 36 MFMAs with NO exp2 gap -- then does mask+exp2+cvt+permlane of
// tile kt into pa for the next iteration. Epilogue drains the last PV.
// V is triple-buffered (PV(kt-1) reads V[(kt-1)%3] while prefetch writes
// V[(kt+1)%3]; a V buffer is rewritten only 3 tiles later, always behind a
// barrier); K stays double-buffered. LDS = 2*8K + 3*8K = 40960B -> exactly
// 4 blocks/CU. Per-tile accumulation order unchanged -> bit-identical.
// T12 in-register P transpose retained (frees pl; required for LDS budget).
// V stays LDS-staged (destaging: 2.5x regression, R5). Typed __shared__
// indexing only (generic char* defeats LDS addressing: +33%, R2/R3).
// Q pre-scaled by 0.125*log2e (folded into qkv-GEMM) -> softmax is bare exp2.
__global__ __launch_bounds__(256, 4)
void attn_kernel(const bf16* __restrict__ qkvb, const bf16* __restrict__ vt,
                 bf16* __restrict__ att) {
  const int o = blockIdx.x;                 // 1024 blocks
  const int xcd = o & 7, s = o >> 3;        // s: 0..127
  const int bh = xcd * 8 + (s & 7);         // XCD-grouped: 8 bh (2 kv heads) per XCD
  const int qt = 15 - (s >> 3);             // big q-tiles dispatched first
  const int h = bh & 31, b = bh >> 5;
  const int kvh = h >> 2;
  const int tid = threadIdx.x, w = tid >> 6, l = tid & 63;
  const int ln = l & 15, g = l >> 4;

  __shared__ __align__(16) bf16 Ks[2][4096];
  __shared__ __align__(16) bf16 Vs[3][4096];

  // staging: 256 threads stage 64x64 K and V tiles via 2 gload16 each
  const int srow = tid >> 3;                // 0..31
  const int sch  = (tid & 7) ^ (srow & 7);  // row&7 == srow&7 for both halves
  const bf16* kg = qkvb + (long)(b*T_ + srow) * NQKV + KOFF + kvh*HD_ + sch*8;
  const bf16* vg = vt + (long)((b*KVH_ + kvh) * HD_ + srow) * T_ + sch*8;
  const int ldsoff = tid * 8;               // elems; +2048 for second half

  // diag-tile q position (within 64-row k-tile) per fragment
  const int qrel0 = (w & 1)*32 + ln;
  const int qrel1 = qrel0 + 16;

  bf16x8 onesf;
  {
    const bf16 ov = (ln == 0) ? (bf16)1.0f : (bf16)0.0f;
#pragma unroll
    for (int i = 0; i < 8; ++i) onesf[i] = ov;
  }

  const int qbase = qt * 128;
  const int nt = qt * 2 + 2;
  const int myNt = qt*2 + 1 + (w >> 1);   // waves 0-1: rows [0,64); 2-3: [64,128)

  const int q0 = qbase + w*32;
  const long qb0 = (long)(b*T_ + q0 + ln) * NQKV + h*HD_;
  const long qb1 = (long)(b*T_ + q0 + 16 + ln) * NQKV + h*HD_;
  bf16x8 qf0a = *(const bf16x8*)&qkvb[qb0 + g*8];
  bf16x8 qf0b = *(const bf16x8*)&qkvb[qb0 + 32 + g*8];
  bf16x8 qf1a = *(const bf16x8*)&qkvb[qb1 + g*8];
  bf16x8 qf1b = *(const bf16x8*)&qkvb[qb1 + 32 + g*8];

  f32x4 oacc0[4], oacc1[4], osum0, osum1;
#pragma unroll
  for (int d = 0; d < 4; ++d) { oacc0[d] = 0.f; oacc1[d] = 0.f; }
  osum0 = 0.f; osum1 = 0.f;

  // carried P fragments (tile kt-1), valid when kt-1 < myNt
  bf16x8 pa0a, pa0b, pa1a, pa1b;

  // prologue: stage tile 0
  gload16(kg, &Ks[0][ldsoff]);
  gload16(kg + (long)32*NQKV, &Ks[0][ldsoff + 2048]);
  gload16(vg, &Vs[0][ldsoff]);
  gload16(vg + (long)32*T_, &Vs[0][ldsoff + 2048]);
  __syncthreads();

  int vprev = 2, vcur = 0, vnext = 1;   // (kt-1)%3, kt%3, (kt+1)%3
  for (int kt = 0; kt < nt; ++kt) {
    const int kcur = kt & 1;
    if (kt + 1 < nt) {
      const int k1 = (kt + 1) * 64;
      gload16(kg + (long)k1 * NQKV,        &Ks[kcur^1][ldsoff]);
      gload16(kg + (long)(k1+32) * NQKV,   &Ks[kcur^1][ldsoff + 2048]);
      gload16(vg + k1,                     &Vs[vnext][ldsoff]);
      gload16(vg + (long)32*T_ + k1,       &Vs[vnext][ldsoff + 2048]);
    }
    const bool doPV = (kt >= 1) && (kt - 1 < myNt);
    const bool doQK = kt < myNt;

    f32x4 sv0[4], sv1[4];
    __builtin_amdgcn_s_setprio(1);
    if (doPV) {
#pragma unroll
      for (int d = 0; d < 4; ++d) {
        const int vrow = d*16 + ln, sw = vrow & 7;
        bf16x8 vf0 = *(const bf16x8*)&Vs[vprev][vrow*64 + (( g    ^ sw) << 3)];
        bf16x8 vf1 = *(const bf16x8*)&Vs[vprev][vrow*64 + (((g+4) ^ sw) << 3)];
        oacc0[d] = __builtin_amdgcn_mfma_f32_16x16x32_bf16(vf0, pa0a, oacc0[d], 0, 0, 0);
        oacc0[d] = __builtin_amdgcn_mfma_f32_16x16x32_bf16(vf1, pa0b, oacc0[d], 0, 0, 0);
        oacc1[d] = __builtin_amdgcn_mfma_f32_16x16x32_bf16(vf0, pa1a, oacc1[d], 0, 0, 0);
        oacc1[d] = __builtin_amdgcn_mfma_f32_16x16x32_bf16(vf1, pa1b, oacc1[d], 0, 0, 0);
      }
      osum0 = __builtin_amdgcn_mfma_f32_16x16x32_bf16(onesf, pa0a, osum0, 0, 0, 0);
      osum0 = __builtin_amdgcn_mfma_f32_16x16x32_bf16(onesf, pa0b, osum0, 0, 0, 0);
      osum1 = __builtin_amdgcn_mfma_f32_16x16x32_bf16(onesf, pa1a, osum1, 0, 0, 0);
      osum1 = __builtin_amdgcn_mfma_f32_16x16x32_bf16(onesf, pa1b, osum1, 0, 0, 0);
    }
    if (doQK) {
#pragma unroll
      for (int c = 0; c < 4; ++c) {
        const int krow = c*16 + ln, sw = krow & 7;
        bf16x8 kf0 = *(const bf16x8*)&Ks[kcur][krow*64 + (( g    ^ sw) << 3)];
        bf16x8 kf1 = *(const bf16x8*)&Ks[kcur][krow*64 + (((g+4) ^ sw) << 3)];
        f32x4 z0 = 0.f, z1 = 0.f;
        z0     = __builtin_amdgcn_mfma_f32_16x16x32_bf16(kf0, qf0a, z0, 0, 0, 0);
        sv0[c] = __builtin_amdgcn_mfma_f32_16x16x32_bf16(kf1, qf0b, z0, 0, 0, 0);
        z1     = __builtin_amdgcn_mfma_f32_16x16x32_bf16(kf0, qf1a, z1, 0, 0, 0);
        sv1[c] = __builtin_amdgcn_mfma_f32_16x16x32_bf16(kf1, qf1b, z1, 0, 0, 0);
      }
    }
    __builtin_amdgcn_s_setprio(0);

    if (doQK) {
      // diag peel: mask-adds only on the wave's last tile (wave-uniform branch)
      if (kt == myNt - 1) {
#pragma unroll
        for (int c = 0; c < 4; ++c)
#pragma unroll
          for (int r = 0; r < 4; ++r) {
            const int krel = c*16 + g*4 + r;
            sv0[c][r] += (krel > qrel0) ? -1e38f : 0.f;
            sv1[c][r] += (krel > qrel1) ? -1e38f : 0.f;
          }
      }
      // softmax: bare exp2 (scale pre-folded into Q)
#pragma unroll
      for (int c = 0; c < 4; ++c)
#pragma unroll
        for (int r = 0; r < 4; ++r) {
          sv0[c][r] = exp2f(sv0[c][r]);
          sv1[c][r] = exp2f(sv1[c][r]);
        }
      // in-register P->PV-fragment transpose (T12): cvt_pk + 4x4 dword
      // transpose across 16-lane groups via permlane32/16 swaps.
      {
        unsigned p0,p1,p2,p3,p4,p5,p6,p7;
        asm("v_cvt_pk_bf16_f32 %0, %1, %2" : "=v"(p0) : "v"(sv0[0][0]), "v"(sv0[0][1]));
        asm("v_cvt_pk_bf16_f32 %0, %1, %2" : "=v"(p1) : "v"(sv0[0][2]), "v"(sv0[0][3]));
        asm("v_cvt_pk_bf16_f32 %0, %1, %2" : "=v"(p2) : "v"(sv0[1][0]), "v"(sv0[1][1]));
        asm("v_cvt_pk_bf16_f32 %0, %1, %2" : "=v"(p3) : "v"(sv0[1][2]), "v"(sv0[1][3]));
        asm("v_cvt_pk_bf16_f32 %0, %1, %2" : "=v"(p4) : "v"(sv0[2][0]), "v"(sv0[2][1]));
        asm("v_cvt_pk_bf16_f32 %0, %1, %2" : "=v"(p5) : "v"(sv0[2][2]), "v"(sv0[2][3]));
        asm("v_cvt_pk_bf16_f32 %0, %1, %2" : "=v"(p6) : "v"(sv0[3][0]), "v"(sv0[3][1]));
        asm("v_cvt_pk_bf16_f32 %0, %1, %2" : "=v"(p7) : "v"(sv0[3][2]), "v"(sv0[3][3]));
        asm("v_permlane32_swap_b32 %0, %1" : "+v"(p0), "+v"(p2));
        asm("v_permlane32_swap_b32 %0, %1" : "+v"(p1), "+v"(p3));
        asm("v_permlane16_swap_b32 %0, %1" : "+v"(p0), "+v"(p2));
        asm("v_permlane16_swap_b32 %0, %1" : "+v"(p1), "+v"(p3));
        asm("v_permlane32_swap_b32 %0, %1" : "+v"(p4), "+v"(p6));
        asm("v_permlane32_swap_b32 %0, %1" : "+v"(p5), "+v"(p7));
        asm("v_permlane16_swap_b32 %0, %1" : "+v"(p4), "+v"(p6));
        asm("v_permlane16_swap_b32 %0, %1" : "+v"(p5), "+v"(p7));
        union { unsigned u[4]; bf16x8 v; } ua, ub;
        ua.u[0]=p0; ua.u[1]=p1; ua.u[2]=p2; ua.u[3]=p3; pa0a = ua.v;
        ub.u[0]=p4; ub.u[1]=p5; ub.u[2]=p6; ub.u[3]=p7; pa0b = ub.v;
      }
      {
        unsigned p0,p1,p2,p3,p4,p5,p6,p7;
        asm("v_cvt_pk_bf16_f32 %0, %1, %2" : "=v"(p0) : "v"(sv1[0][0]), "v"(sv1[0][1]));
        asm("v_cvt_pk_bf16_f32 %0, %1, %2" : "=v"(p1) : "v"(sv1[0][2]), "v"(sv1[0][3]));
        asm("v_cvt_pk_bf16_f32 %0, %1, %2" : "=v"(p2) : "v"(sv1[1][0]), "v"(sv1[1][1]));
        asm("v_cvt_pk_bf16_f32 %0, %1, %2" : "=v"(p3) : "v"(sv1[1][2]), "v"(sv1[1][3]));
        asm("v_cvt_pk_bf16_f32 %0, %1, %2" : "=v"(p4) : "v"(sv1[2][0]), "v"(sv1[2][1]));
        asm("v_cvt_pk_bf16_f32 %0, %1, %2" : "=v"(p5) : "v"(sv1[2][2]), "v"(sv1[2][3]));
        asm("v_cvt_pk_bf16_f32 %0, %1, %2" : "=v"(p6) : "v"(sv1[3][0]), "v"(sv1[3][1]));
        asm("v_cvt_pk_bf16_f32 %0, %1, %2" : "=v"(p7) : "v"(sv1[3][2]), "v"(sv1[3][3]));
        asm("v_permlane32_swap_b32 %0, %1" : "+v"(p0), "+v"(p2));
        asm("v_permlane32_swap_b32 %0, %1" : "+v"(p1), "+v"(p3));
        asm("v_permlane16_swap_b32 %0, %1" : "+v"(p0), "+v"(p2));
        asm("v_permlane16_swap_b32 %0, %1" : "+v"(p1), "+v"(p3));
        asm("v_permlane32_swap_b32 %0, %1" : "+v"(p4), "+v"(p6));
        asm("v_permlane32_swap_b32 %0, %1" : "+v"(p5), "+v"(p7));
        asm("v_permlane16_swap_b32 %0, %1" : "+v"(p4), "+v"(p6));
        asm("v_permlane16_swap_b32 %0, %1" : "+v"(p5), "+v"(p7));
        union { unsigned u[4]; bf16x8 v; } ua, ub;
        ua.u[0]=p0; ua.u[1]=p1; ua.u[2]=p2; ua.u[3]=p3; pa1a = ua.v;
        ub.u[0]=p4; ub.u[1]=p5; ub.u[2]=p6; ub.u[3]=p7; pa1b = ub.v;
      }
    }
    __syncthreads();
    const int t = vprev; vprev = vcur; vcur = vnext; vnext = t;
  }

  // epilogue: drain PV of the last computed tile (waves with myNt == nt)
  if (nt - 1 < myNt) {
#pragma unroll
    for (int d = 0; d < 4; ++d) {
      const int vrow = d*16 + ln, sw = vrow & 7;
      bf16x8 vf0 = *(const bf16x8*)&Vs[vprev][vrow*64 + (( g    ^ sw) << 3)];
      bf16x8 vf1 = *(const bf16x8*)&Vs[vprev][vrow*64 + (((g+4) ^ sw) << 3)];
      oacc0[d] = __builtin_amdgcn_mfma_f32_16x16x32_bf16(vf0, pa0a, oacc0[d], 0, 0, 0);
      oacc0[d] = __builtin_amdgcn_mfma_f32_16x16x32_bf16(vf1, pa0b, oacc0[d], 0, 0, 0);
      oacc1[d] = __builtin_amdgcn_mfma_f32_16x16x32_bf16(vf0, pa1a, oacc1[d], 0, 0, 0);
      oacc1[d] = __builtin_amdgcn_mfma_f32_16x16x32_bf16(vf1, pa1b, oacc1[d], 0, 0, 0);
    }
    osum0 = __builtin_amdgcn_mfma_f32_16x16x32_bf16(onesf, pa0a, osum0, 0, 0, 0);
    osum0 = __builtin_amdgcn_mfma_f32_16x16x32_bf16(onesf, pa0b, osum0, 0, 0, 0);
    osum1 = __builtin_amdgcn_mfma_f32_16x16x32_bf16(onesf, pa1a, osum1, 0, 0, 0);
    osum1 = __builtin_amdgcn_mfma_f32_16x16x32_bf16(onesf, pa1b, osum1, 0, 0, 0);
  }

  {
    const float lsum = __shfl(osum0[0], ln);
    const float inv = 1.f / lsum;
    const long ob = (long)(b*T_ + q0 + ln) * DIM_ + h*HD_;
#pragma unroll
    for (int d = 0; d < 4; ++d) {
      bf16x4 ov;
#pragma unroll
      for (int r = 0; r < 4; ++r) ov[r] = (bf16)(oacc0[d][r] * inv);
      *(bf16x4*)&att[ob + d*16 + g*4] = ov;
    }
  }
  {
    const float lsum = __shfl(osum1[0], ln);
    const float inv = 1.f / lsum;
    const long ob = (long)(b*T_ + q0 + 16 + ln) * DIM_ + h*HD_;
#pragma unroll
    for (int d = 0; d < 4; ++d) {
      bf16x4 ov;
#pragma unroll
      for (int r = 0; r < 4; ++r) ov[r] = (bf16)(oacc1[d][r] * inv);
      *(bf16x4*)&att[ob + d*16 + g*4] = ov;
    }
  }
}

// ---------------- launch ----------------
extern "C" void kernel_launch(void* const* d_in, const int* in_sizes, int n_in,
                              void* d_out, int out_size, void* d_ws, size_t ws_size,
                              hipStream_t stream) {
  const float* x  = (const float*)d_in[0];
  const float* wq = (const float*)d_in[1];
  const float* wk = (const float*)d_in[2];
  const float* wv = (const float*)d_in[3];
  const float* wo = (const float*)d_in[4];
  const float* fc = (const float*)d_in[5];
  const float* fs = (const float*)d_in[6];

  char* ws = (char*)d_ws;
  bf16* xb   = (bf16*)(ws);
  bf16* wT   = (bf16*)(ws + 16777216);
  bf16* woT  = (bf16*)(ws + 29360128);
  bf16* qkvb = (bf16*)(ws + 37748736);
  bf16* vtb  = (bf16*)(ws + 62914560);
  bf16* att  = (bf16*)(ws + 67108864);
  // transposed RoPE tables live in the att region (dead until attn writes it)
  float* fcT = (float*)(ws + 67108864);
  float* fsT = fcT + 32*2048;

  dim3 tb(32, 8);
  prep_kernel<<<18560, tb, 0, stream>>>(x, wq, wk, wv, wo, fc, fs, xb, wT, woT, fcT, fsT);

  // qkv GEMM with fused RoPE (+Q pre-scale) + V^T epilogue
  gemm_bt<1><<<(BT_ROWS/128) * (NQKV/128), 256, 0, stream>>>(
      xb, wT, qkvb, BT_ROWS, NQKV, DIM_, fcT, fsT, vtb);

  attn_kernel<<<1024, 256, 0, stream>>>(qkvb, vtb, att);

  gemm_bt<0><<<(BT_ROWS/128) * (DIM_/128), 256, 0, stream>>>(
      att, woT, d_out, BT_ROWS, DIM_, DIM_, nullptr, nullptr, nullptr);
}

// Round 9
// 186.057 us; speedup vs baseline: 1.0458x; 1.0458x over previous
//
#include <hip/hip_runtime.h>
#include <stdint.h>

typedef __bf16 bf16;
typedef __attribute__((ext_vector_type(8))) __bf16 bf16x8;
typedef __attribute__((ext_vector_type(4))) __bf16 bf16x4;
typedef __attribute__((ext_vector_type(4))) float f32x4;
typedef __attribute__((ext_vector_type(16))) float f32x16;
typedef __attribute__((ext_vector_type(4))) unsigned short us4;

constexpr int B_   = 2;
constexpr int T_   = 2048;
constexpr int DIM_ = 2048;
constexpr int H_   = 32;
constexpr int KVH_ = 8;
constexpr int HD_  = 64;
constexpr int BT_ROWS = B_ * T_;            // 4096
constexpr int NQKV = H_*HD_ + 2*KVH_*HD_;   // 3072
constexpr int KOFF = H_*HD_;                // 2048
constexpr int VOFF = H_*HD_ + KVH_*HD_;     // 2560

#define DEV __device__ __forceinline__

DEV void gload16(const void* g, void* l) {
  __builtin_amdgcn_global_load_lds((const __attribute__((address_space(1))) void*)g,
                                   (__attribute__((address_space(3))) void*)l,
                                   16, 0, 0);
}

// ---------------- fused prep: x cvt + 4x weight transpose + RoPE table transpose ----------------
__global__ void prep_kernel(const float* __restrict__ x,
                            const float* __restrict__ wq, const float* __restrict__ wk,
                            const float* __restrict__ wv, const float* __restrict__ wo,
                            const float* __restrict__ fc, const float* __restrict__ fs,
                            bf16* __restrict__ xb, bf16* __restrict__ wT,
                            bf16* __restrict__ woT,
                            float* __restrict__ fcT, float* __restrict__ fsT) {
  const int id = blockIdx.x;
  const int tid = threadIdx.y * 32 + threadIdx.x;
  if (id < 8192) {
    int gid = id * 256 + tid;
    float4 f = ((const float4*)x)[gid];
    bf16x4 o;
    o[0] = (bf16)f.x; o[1] = (bf16)f.y; o[2] = (bf16)f.z; o[3] = (bf16)f.w;
    ((bf16x4*)xb)[gid] = o;
    return;
  }
  __shared__ float tile[32][33];
  int td = id - 8192;
  int tx = threadIdx.x, ty = threadIdx.y;
  if (td < 10240) {
    const float* in; bf16* out; int C, bid;
    if (td < 4096)      { in = wq; out = wT;               C = 2048; bid = td; }
    else if (td < 5120) { in = wk; out = wT + 2048*2048;   C = 512;  bid = td - 4096; }
    else if (td < 6144) { in = wv; out = wT + 2560*2048;   C = 512;  bid = td - 5120; }
    else                { in = wo; out = woT;              C = 2048; bid = td - 6144; }
    const int R = 2048;
    int ct = C / 32;
    int bx = bid % ct, by = bid / ct;
#pragma unroll
    for (int i = ty; i < 32; i += 8)
      tile[i][tx] = in[(by*32 + i) * C + bx*32 + tx];
    __syncthreads();
#pragma unroll
    for (int i = ty; i < 32; i += 8)
      out[(bx*32 + i) * R + by*32 + tx] = (bf16)tile[tx][i];
  } else {
    // RoPE table transpose: [2048][32] f32 -> [32][2048] f32
    int tt = td - 10240;                  // [0,128)
    const float* in = (tt >= 64) ? fs : fc;
    float* outf = (tt >= 64) ? fsT : fcT;
    int bid = tt & 63;                    // t-tile index
#pragma unroll
    for (int i = ty; i < 32; i += 8)
      tile[i][tx] = in[(bid*32 + i) * 32 + tx];
    __syncthreads();
#pragma unroll
    for (int i = ty; i < 32; i += 8)
      outf[i * 2048 + bid*32 + tx] = tile[tx][i];
  }
}

// ---------------- GEMM: C[M,N] = A[M,K] * B[K,N], B given transposed (N,K) ----------------
// 128x128 tile, BK=64, 4 waves, single-buffer 2-barrier, 32x32x16 MFMA.
// MODE 0: plain f32 C store (out-proj), (256,2). MODE 1: qkv fused epilogue
// (RoPE via adjacent-lane shfl + transposed tables; V written as V^T), (256,3).
// MODE 1 folds the attention softmax scale (0.125*log2e) into the Q region.
template<int MODE>
__global__ __launch_bounds__(256, MODE == 1 ? 3 : 2)
void gemm_bt(const bf16* __restrict__ A, const bf16* __restrict__ BTm,
             void* __restrict__ Cv, int M, int N, int K,
             const float* __restrict__ fcT, const float* __restrict__ fsT,
             bf16* __restrict__ vt) {
  __shared__ __align__(16) bf16 As[128 * 64];
  __shared__ __align__(16) bf16 Bs[128 * 64];
  const int nbn = N >> 7;
  const int bm = blockIdx.x / nbn, bn = blockIdx.x % nbn;
  const int tid = threadIdx.x;
  const int w = tid >> 6, l = tid & 63;
  const int wr = w >> 1, wc = w & 1;
  const int lr = l & 31;              // row/col within 32x32 fragment
  const int hi = l >> 5;              // k-chunk select (0/1)
  const int crow = l >> 3;            // staging: row within 8-row group
  const int cch  = (l & 7) ^ crow;    // staging: inverse-swizzled source chunk

  f32x16 acc[2][2];
#pragma unroll
  for (int i = 0; i < 2; ++i)
#pragma unroll
    for (int j = 0; j < 2; ++j) acc[i][j] = 0.f;

  const bf16* ap[4];
  const bf16* bp[4];
#pragma unroll
  for (int i = 0; i < 4; ++i) {
    int row = (w*4 + i) * 8 + crow;
    ap[i] = A   + (long)(bm*128 + row) * K + cch*8;
    bp[i] = BTm + (long)(bn*128 + row) * K + cch*8;
  }
  int aoff[4][2], boff[4][2];
#pragma unroll
  for (int ks = 0; ks < 4; ++ks)
#pragma unroll
    for (int i = 0; i < 2; ++i) {
      int arow = wr*64 + i*32 + lr;
      int brow = wc*64 + i*32 + lr;
      aoff[ks][i] = arow*64 + (((2*ks + hi) ^ (arow & 7)) << 3);
      boff[ks][i] = brow*64 + (((2*ks + hi) ^ (brow & 7)) << 3);
    }

  for (int k0 = 0; k0 < K; k0 += 64) {
#pragma unroll
    for (int i = 0; i < 4; ++i) {
      gload16(ap[i], &As[(w*4 + i) * 512]);
      gload16(bp[i], &Bs[(w*4 + i) * 512]);
      ap[i] += 64; bp[i] += 64;
    }
    __syncthreads();
#pragma unroll
    for (int ks = 0; ks < 4; ++ks) {
      bf16x8 af[2], bfr[2];
#pragma unroll
      for (int i = 0; i < 2; ++i) af[i]  = *(const bf16x8*)&As[aoff[ks][i]];
#pragma unroll
      for (int j = 0; j < 2; ++j) bfr[j] = *(const bf16x8*)&Bs[boff[ks][j]];
#pragma unroll
      for (int i = 0; i < 2; ++i)
#pragma unroll
        for (int j = 0; j < 2; ++j)
          acc[i][j] = __builtin_amdgcn_mfma_f32_32x32x16_bf16(af[i], bfr[j], acc[i][j], 0, 0, 0);
    }
    __syncthreads();
  }

  // epilogue: C/D layout col = l&31, row = (reg&3) + 8*(reg>>2) + 4*(l>>5)
  const int row0 = bm*128 + wr*64, col0 = bn*128 + wc*64;
  if (MODE == 0) {
#pragma unroll
    for (int i = 0; i < 2; ++i)
#pragma unroll
      for (int j = 0; j < 2; ++j)
#pragma unroll
        for (int reg = 0; reg < 16; ++reg) {
          int rr = row0 + i*32 + (reg & 3) + 8*(reg >> 2) + 4*hi;
          int cc = col0 + j*32 + lr;
          ((float*)Cv)[(long)rr * N + cc] = acc[i][j][reg];
        }
  } else {
    if (col0 < VOFF) {
      // RoPE (q and k regions): pair = adjacent lanes; tables transposed -> float4 t-runs
      const float sgn = (lr & 1) ? 1.f : -1.f;
#pragma unroll
      for (int i = 0; i < 2; ++i) {
        const int tb0 = ((row0 + i*32) & (T_ - 1)) + 4*hi;
#pragma unroll
        for (int j = 0; j < 2; ++j) {
          const int cc = col0 + j*32 + lr;
          // fold softmax scale*log2(e) into Q (q region only)
          const float qsc = (col0 + j*32 < KOFF) ? 0.18033688f : 1.0f;
          const int p0 = (cc & 63) >> 1;
          const float* fct = fcT + p0*2048 + tb0;
          const float* fst = fsT + p0*2048 + tb0;
#pragma unroll
          for (int q = 0; q < 4; ++q) {
            float4 c4 = *(const float4*)(fct + 8*q);
            float4 s4 = *(const float4*)(fst + 8*q);
#pragma unroll
            for (int r = 0; r < 4; ++r) {
              float v = acc[i][j][q*4 + r];
              float other = __shfl_xor(v, 1);
              float cse = (&c4.x)[r], sse = (&s4.x)[r];
              float out = fmaf(sgn * other, sse, v * cse) * qsc;
              const int rr = row0 + i*32 + r + 8*q + 4*hi;
              ((bf16*)Cv)[(long)rr * N + cc] = (bf16)out;
            }
          }
        }
      }
    } else {
      // V region: write V^T directly (t-contiguous 4-packs)
      const int bglob = row0 >> 11;
#pragma unroll
      for (int i = 0; i < 2; ++i)
#pragma unroll
        for (int j = 0; j < 2; ++j) {
          const int vo = col0 + j*32 + lr - VOFF;
          const long vbase = (long)((bglob*KVH_ + (vo >> 6))*HD_ + (vo & 63)) * T_;
#pragma unroll
          for (int q = 0; q < 4; ++q) {
            bf16x4 pk;
#pragma unroll
            for (int r = 0; r < 4; ++r) pk[r] = (bf16)acc[i][j][q*4 + r];
            const int t = ((row0 + i*32) & (T_ - 1)) + 8*q + 4*hi;
            *(bf16x4*)&vt[vbase + t] = pk;
          }
        }
    }
  }
}

// ---------------- GQA causal flash attention ----------------
// EXACT R6 state (best measured: attn 71.5us, total 186.4us).
// 1024 blocks x 256 threads (4 waves), ONE q-tile (128 rows) per block,
// each wave owns 32 q-rows as TWO 16-row fragments; K/V fragments read from
// LDS once feed BOTH fragments' MFMAs. LDS 52224B -> 3 blocks/CU.
// Big-first dispatch (qt descends), XCD-grouped bh.
// Session ledger (do NOT retry): generic char* LDS hoists (+33%, R2/R3);
// V-destaging (2.5x, R5); split-barrier counted-vmcnt (+35%, R2);
// T12 in-reg P transpose via unions (scratch spill, +3, R7); T15 carried-pa
// pipeline (scratch spill, +11, R8); occupancy changes (null, R1/R6).
// pl LDS roundtrip for P redistribution is the verified-fastest form.
// Q pre-scaled by 0.125*log2e (folded into qkv-GEMM) -> softmax is bare exp2.
// Diag peel (mask-adds only on wave's last tile) + MFMA ones-row row-sum.
__global__ __launch_bounds__(256, 3)
void attn_kernel(const bf16* __restrict__ qkvb, const bf16* __restrict__ vt,
                 bf16* __restrict__ att) {
  const int o = blockIdx.x;                 // 1024 blocks
  const int xcd = o & 7, s = o >> 3;        // s: 0..127
  const int bh = xcd * 8 + (s & 7);         // XCD-grouped: 8 bh (2 kv heads) per XCD
  const int qt = 15 - (s >> 3);             // big q-tiles dispatched first
  const int h = bh & 31, b = bh >> 5;
  const int kvh = h >> 2;
  const int tid = threadIdx.x, w = tid >> 6, l = tid & 63;
  const int ln = l & 15, g = l >> 4;

  __shared__ __align__(16) bf16 Ks[2][4096];
  __shared__ __align__(16) bf16 Vs[2][4096];
  __shared__ __align__(16) bf16 pl[4][32][76];

  // staging: 256 threads stage 64x64 K and V tiles via 2 gload16 each
  const int srow = tid >> 3;                // 0..31
  const int sch  = (tid & 7) ^ (srow & 7);  // row&7 == srow&7 for both halves
  const bf16* kg = qkvb + (long)(b*T_ + srow) * NQKV + KOFF + kvh*HD_ + sch*8;
  const bf16* vg = vt + (long)((b*KVH_ + kvh) * HD_ + srow) * T_ + sch*8;
  const int ldsoff = tid * 8;               // elems; +2048 for second half

  // diag-tile q position (within 64-row k-tile) per fragment
  const int qrel0 = (w & 1)*32 + ln;
  const int qrel1 = qrel0 + 16;

  bf16x8 onesf;
  {
    const bf16 ov = (ln == 0) ? (bf16)1.0f : (bf16)0.0f;
#pragma unroll
    for (int i = 0; i < 8; ++i) onesf[i] = ov;
  }

  const int qbase = qt * 128;
  const int nt = qt * 2 + 2;
  const int myNt = qt*2 + 1 + (w >> 1);   // waves 0-1: rows [0,64); 2-3: [64,128)

  const int q0 = qbase + w*32;
  const long qb0 = (long)(b*T_ + q0 + ln) * NQKV + h*HD_;
  const long qb1 = (long)(b*T_ + q0 + 16 + ln) * NQKV + h*HD_;
  bf16x8 qf0a = *(const bf16x8*)&qkvb[qb0 + g*8];
  bf16x8 qf0b = *(const bf16x8*)&qkvb[qb0 + 32 + g*8];
  bf16x8 qf1a = *(const bf16x8*)&qkvb[qb1 + g*8];
  bf16x8 qf1b = *(const bf16x8*)&qkvb[qb1 + 32 + g*8];

  f32x4 oacc0[4], oacc1[4], osum0, osum1;
#pragma unroll
  for (int d = 0; d < 4; ++d) { oacc0[d] = 0.f; oacc1[d] = 0.f; }
  osum0 = 0.f; osum1 = 0.f;

  gload16(kg, &Ks[0][ldsoff]);
  gload16(kg + (long)32*NQKV, &Ks[0][ldsoff + 2048]);
  gload16(vg, &Vs[0][ldsoff]);
  gload16(vg + (long)32*T_, &Vs[0][ldsoff + 2048]);
  __syncthreads();

  int cur = 0;
  for (int kt = 0; kt < nt; ++kt) {
    if (kt + 1 < nt) {
      const int k1 = (kt + 1) * 64;
      gload16(kg + (long)k1 * NQKV,        &Ks[cur^1][ldsoff]);
      gload16(kg + (long)(k1+32) * NQKV,   &Ks[cur^1][ldsoff + 2048]);
      gload16(vg + k1,                     &Vs[cur^1][ldsoff]);
      gload16(vg + (long)32*T_ + k1,       &Vs[cur^1][ldsoff + 2048]);
    }
    if (kt < myNt) {
      f32x4 sv0[4], sv1[4];
      __builtin_amdgcn_s_setprio(1);
#pragma unroll
      for (int c = 0; c < 4; ++c) {
        const int krow = c*16 + ln, sw = krow & 7;
        bf16x8 kf0 = *(const bf16x8*)&Ks[cur][krow*64 + (( g    ^ sw) << 3)];
        bf16x8 kf1 = *(const bf16x8*)&Ks[cur][krow*64 + (((g+4) ^ sw) << 3)];
        f32x4 z0 = 0.f, z1 = 0.f;
        z0     = __builtin_amdgcn_mfma_f32_16x16x32_bf16(kf0, qf0a, z0, 0, 0, 0);
        sv0[c] = __builtin_amdgcn_mfma_f32_16x16x32_bf16(kf1, qf0b, z0, 0, 0, 0);
        z1     = __builtin_amdgcn_mfma_f32_16x16x32_bf16(kf0, qf1a, z1, 0, 0, 0);
        sv1[c] = __builtin_amdgcn_mfma_f32_16x16x32_bf16(kf1, qf1b, z1, 0, 0, 0);
      }
      __builtin_amdgcn_s_setprio(0);

      // diag peel: mask-adds only on the wave's last tile (wave-uniform branch)
      if (kt == myNt - 1) {
#pragma unroll
        for (int c = 0; c < 4; ++c)
#pragma unroll
          for (int r = 0; r < 4; ++r) {
            const int krel = c*16 + g*4 + r;
            sv0[c][r] += (krel > qrel0) ? -1e38f : 0.f;
            sv1[c][r] += (krel > qrel1) ? -1e38f : 0.f;
          }
      }

      // softmax: bare exp2 (scale pre-folded into Q) -> pack -> pl roundtrip
#pragma unroll
      for (int c = 0; c < 4; ++c) {
        bf16x4 pk0, pk1;
#pragma unroll
        for (int r = 0; r < 4; ++r) {
          pk0[r] = (bf16)exp2f(sv0[c][r]);
          pk1[r] = (bf16)exp2f(sv1[c][r]);
        }
        *(bf16x4*)&pl[w][ln][c*16 + g*4]      = pk0;
        *(bf16x4*)&pl[w][16 + ln][c*16 + g*4] = pk1;
      }

      bf16x8 pa0a = *(const bf16x8*)&pl[w][ln][g*8];
      bf16x8 pa0b = *(const bf16x8*)&pl[w][ln][32 + g*8];
      bf16x8 pa1a = *(const bf16x8*)&pl[w][16 + ln][g*8];
      bf16x8 pa1b = *(const bf16x8*)&pl[w][16 + ln][32 + g*8];

      __builtin_amdgcn_s_setprio(1);
#pragma unroll
      for (int d = 0; d < 4; ++d) {
        const int vrow = d*16 + ln, sw = vrow & 7;
        bf16x8 vf0 = *(const bf16x8*)&Vs[cur][vrow*64 + (( g    ^ sw) << 3)];
        bf16x8 vf1 = *(const bf16x8*)&Vs[cur][vrow*64 + (((g+4) ^ sw) << 3)];
        oacc0[d] = __builtin_amdgcn_mfma_f32_16x16x32_bf16(vf0, pa0a, oacc0[d], 0, 0, 0);
        oacc0[d] = __builtin_amdgcn_mfma_f32_16x16x32_bf16(vf1, pa0b, oacc0[d], 0, 0, 0);
        oacc1[d] = __builtin_amdgcn_mfma_f32_16x16x32_bf16(vf0, pa1a, oacc1[d], 0, 0, 0);
        oacc1[d] = __builtin_amdgcn_mfma_f32_16x16x32_bf16(vf1, pa1b, oacc1[d], 0, 0, 0);
      }
      osum0 = __builtin_amdgcn_mfma_f32_16x16x32_bf16(onesf, pa0a, osum0, 0, 0, 0);
      osum0 = __builtin_amdgcn_mfma_f32_16x16x32_bf16(onesf, pa0b, osum0, 0, 0, 0);
      osum1 = __builtin_amdgcn_mfma_f32_16x16x32_bf16(onesf, pa1a, osum1, 0, 0, 0);
      osum1 = __builtin_amdgcn_mfma_f32_16x16x32_bf16(onesf, pa1b, osum1, 0, 0, 0);
      __builtin_amdgcn_s_setprio(0);
    }
    __syncthreads();
    cur ^= 1;
  }

  {
    const float lsum = __shfl(osum0[0], ln);
    const float inv = 1.f / lsum;
    const long ob = (long)(b*T_ + q0 + ln) * DIM_ + h*HD_;
#pragma unroll
    for (int d = 0; d < 4; ++d) {
      bf16x4 ov;
#pragma unroll
      for (int r = 0; r < 4; ++r) ov[r] = (bf16)(oacc0[d][r] * inv);
      *(bf16x4*)&att[ob + d*16 + g*4] = ov;
    }
  }
  {
    const float lsum = __shfl(osum1[0], ln);
    const float inv = 1.f / lsum;
    const long ob = (long)(b*T_ + q0 + 16 + ln) * DIM_ + h*HD_;
#pragma unroll
    for (int d = 0; d < 4; ++d) {
      bf16x4 ov;
#pragma unroll
      for (int r = 0; r < 4; ++r) ov[r] = (bf16)(oacc1[d][r] * inv);
      *(bf16x4*)&att[ob + d*16 + g*4] = ov;
    }
  }
}

// ---------------- launch ----------------
extern "C" void kernel_launch(void* const* d_in, const int* in_sizes, int n_in,
                              void* d_out, int out_size, void* d_ws, size_t ws_size,
                              hipStream_t stream) {
  const float* x  = (const float*)d_in[0];
  const float* wq = (const float*)d_in[1];
  const float* wk = (const float*)d_in[2];
  const float* wv = (const float*)d_in[3];
  const float* wo = (const float*)d_in[4];
  const float* fc = (const float*)d_in[5];
  const float* fs = (const float*)d_in[6];

  char* ws = (char*)d_ws;
  bf16* xb   = (bf16*)(ws);
  bf16* wT   = (bf16*)(ws + 16777216);
  bf16* woT  = (bf16*)(ws + 29360128);
  bf16* qkvb = (bf16*)(ws + 37748736);
  bf16* vtb  = (bf16*)(ws + 62914560);
  bf16* att  = (bf16*)(ws + 67108864);
  // transposed RoPE tables live in the att region (dead until attn writes it)
  float* fcT = (float*)(ws + 67108864);
  float* fsT = fcT + 32*2048;

  dim3 tb(32, 8);
  prep_kernel<<<18560, tb, 0, stream>>>(x, wq, wk, wv, wo, fc, fs, xb, wT, woT, fcT, fsT);

  // qkv GEMM with fused RoPE (+Q pre-scale) + V^T epilogue
  gemm_bt<1><<<(BT_ROWS/128) * (NQKV/128), 256, 0, stream>>>(
      xb, wT, qkvb, BT_ROWS, NQKV, DIM_, fcT, fsT, vtb);

  attn_kernel<<<1024, 256, 0, stream>>>(qkvb, vtb, att);

  gemm_bt<0><<<(BT_ROWS/128) * (DIM_/128), 256, 0, stream>>>(
      att, woT, d_out, BT_ROWS, DIM_, DIM_, nullptr, nullptr, nullptr);
}

// Round 10
// 185.455 us; speedup vs baseline: 1.0492x; 1.0032x over previous
//
#include <hip/hip_runtime.h>
#include <stdint.h>

typedef __bf16 bf16;
typedef __attribute__((ext_vector_type(8))) __bf16 bf16x8;
typedef __attribute__((ext_vector_type(4))) __bf16 bf16x4;
typedef __attribute__((ext_vector_type(4))) float f32x4;
typedef __attribute__((ext_vector_type(16))) float f32x16;
typedef __attribute__((ext_vector_type(4))) unsigned int u32x4;

constexpr int B_   = 2;
constexpr int T_   = 2048;
constexpr int DIM_ = 2048;
constexpr int H_   = 32;
constexpr int KVH_ = 8;
constexpr int HD_  = 64;
constexpr int BT_ROWS = B_ * T_;            // 4096
constexpr int NQKV = H_*HD_ + 2*KVH_*HD_;   // 3072
constexpr int KOFF = H_*HD_;                // 2048
constexpr int VOFF = H_*HD_ + KVH_*HD_;     // 2560

#define DEV __device__ __forceinline__

DEV void gload16(const void* g, void* l) {
  __builtin_amdgcn_global_load_lds((const __attribute__((address_space(1))) void*)g,
                                   (__attribute__((address_space(3))) void*)l,
                                   16, 0, 0);
}

// ---------------- fused prep: x cvt + 4x weight transpose + RoPE table transpose ----------------
__global__ void prep_kernel(const float* __restrict__ x,
                            const float* __restrict__ wq, const float* __restrict__ wk,
                            const float* __restrict__ wv, const float* __restrict__ wo,
                            const float* __restrict__ fc, const float* __restrict__ fs,
                            bf16* __restrict__ xb, bf16* __restrict__ wT,
                            bf16* __restrict__ woT,
                            float* __restrict__ fcT, float* __restrict__ fsT) {
  const int id = blockIdx.x;
  const int tid = threadIdx.y * 32 + threadIdx.x;
  if (id < 8192) {
    int gid = id * 256 + tid;
    float4 f = ((const float4*)x)[gid];
    bf16x4 o;
    o[0] = (bf16)f.x; o[1] = (bf16)f.y; o[2] = (bf16)f.z; o[3] = (bf16)f.w;
    ((bf16x4*)xb)[gid] = o;
    return;
  }
  __shared__ float tile[32][33];
  int td = id - 8192;
  int tx = threadIdx.x, ty = threadIdx.y;
  if (td < 10240) {
    const float* in; bf16* out; int C, bid;
    if (td < 4096)      { in = wq; out = wT;               C = 2048; bid = td; }
    else if (td < 5120) { in = wk; out = wT + 2048*2048;   C = 512;  bid = td - 4096; }
    else if (td < 6144) { in = wv; out = wT + 2560*2048;   C = 512;  bid = td - 5120; }
    else                { in = wo; out = woT;              C = 2048; bid = td - 6144; }
    const int R = 2048;
    int ct = C / 32;
    int bx = bid % ct, by = bid / ct;
#pragma unroll
    for (int i = ty; i < 32; i += 8)
      tile[i][tx] = in[(by*32 + i) * C + bx*32 + tx];
    __syncthreads();
#pragma unroll
    for (int i = ty; i < 32; i += 8)
      out[(bx*32 + i) * R + by*32 + tx] = (bf16)tile[tx][i];
  } else {
    // RoPE table transpose: [2048][32] f32 -> [32][2048] f32
    int tt = td - 10240;                  // [0,128)
    const float* in = (tt >= 64) ? fs : fc;
    float* outf = (tt >= 64) ? fsT : fcT;
    int bid = tt & 63;                    // t-tile index
#pragma unroll
    for (int i = ty; i < 32; i += 8)
      tile[i][tx] = in[(bid*32 + i) * 32 + tx];
    __syncthreads();
#pragma unroll
    for (int i = ty; i < 32; i += 8)
      outf[i * 2048 + bid*32 + tx] = tile[tx][i];
  }
}

// ---------------- GEMM: C[M,N] = A[M,K] * B[K,N], B given transposed (N,K) ----------------
// 128x128 tile, BK=64, 4 waves, single-buffer 2-barrier, 32x32x16 MFMA.
// MODE 0: plain f32 C store (out-proj), (256,2). MODE 1: qkv fused epilogue
// (RoPE via adjacent-lane shfl + transposed tables; V written as V^T), (256,3).
// MODE 1 folds the attention softmax scale (0.125*log2e) into the Q region.
template<int MODE>
__global__ __launch_bounds__(256, MODE == 1 ? 3 : 2)
void gemm_bt(const bf16* __restrict__ A, const bf16* __restrict__ BTm,
             void* __restrict__ Cv, int M, int N, int K,
             const float* __restrict__ fcT, const float* __restrict__ fsT,
             bf16* __restrict__ vt) {
  __shared__ __align__(16) bf16 As[128 * 64];
  __shared__ __align__(16) bf16 Bs[128 * 64];
  const int nbn = N >> 7;
  const int bm = blockIdx.x / nbn, bn = blockIdx.x % nbn;
  const int tid = threadIdx.x;
  const int w = tid >> 6, l = tid & 63;
  const int wr = w >> 1, wc = w & 1;
  const int lr = l & 31;              // row/col within 32x32 fragment
  const int hi = l >> 5;              // k-chunk select (0/1)
  const int crow = l >> 3;            // staging: row within 8-row group
  const int cch  = (l & 7) ^ crow;    // staging: inverse-swizzled source chunk

  f32x16 acc[2][2];
#pragma unroll
  for (int i = 0; i < 2; ++i)
#pragma unroll
    for (int j = 0; j < 2; ++j) acc[i][j] = 0.f;

  const bf16* ap[4];
  const bf16* bp[4];
#pragma unroll
  for (int i = 0; i < 4; ++i) {
    int row = (w*4 + i) * 8 + crow;
    ap[i] = A   + (long)(bm*128 + row) * K + cch*8;
    bp[i] = BTm + (long)(bn*128 + row) * K + cch*8;
  }
  int aoff[4][2], boff[4][2];
#pragma unroll
  for (int ks = 0; ks < 4; ++ks)
#pragma unroll
    for (int i = 0; i < 2; ++i) {
      int arow = wr*64 + i*32 + lr;
      int brow = wc*64 + i*32 + lr;
      aoff[ks][i] = arow*64 + (((2*ks + hi) ^ (arow & 7)) << 3);
      boff[ks][i] = brow*64 + (((2*ks + hi) ^ (brow & 7)) << 3);
    }

  for (int k0 = 0; k0 < K; k0 += 64) {
#pragma unroll
    for (int i = 0; i < 4; ++i) {
      gload16(ap[i], &As[(w*4 + i) * 512]);
      gload16(bp[i], &Bs[(w*4 + i) * 512]);
      ap[i] += 64; bp[i] += 64;
    }
    __syncthreads();
#pragma unroll
    for (int ks = 0; ks < 4; ++ks) {
      bf16x8 af[2], bfr[2];
#pragma unroll
      for (int i = 0; i < 2; ++i) af[i]  = *(const bf16x8*)&As[aoff[ks][i]];
#pragma unroll
      for (int j = 0; j < 2; ++j) bfr[j] = *(const bf16x8*)&Bs[boff[ks][j]];
#pragma unroll
      for (int i = 0; i < 2; ++i)
#pragma unroll
        for (int j = 0; j < 2; ++j)
          acc[i][j] = __builtin_amdgcn_mfma_f32_32x32x16_bf16(af[i], bfr[j], acc[i][j], 0, 0, 0);
    }
    __syncthreads();
  }

  // epilogue: C/D layout col = l&31, row = (reg&3) + 8*(reg>>2) + 4*(l>>5)
  const int row0 = bm*128 + wr*64, col0 = bn*128 + wc*64;
  if (MODE == 0) {
#pragma unroll
    for (int i = 0; i < 2; ++i)
#pragma unroll
      for (int j = 0; j < 2; ++j)
#pragma unroll
        for (int reg = 0; reg < 16; ++reg) {
          int rr = row0 + i*32 + (reg & 3) + 8*(reg >> 2) + 4*hi;
          int cc = col0 + j*32 + lr;
          ((float*)Cv)[(long)rr * N + cc] = acc[i][j][reg];
        }
  } else {
    if (col0 < VOFF) {
      // RoPE (q and k regions): pair = adjacent lanes; tables transposed -> float4 t-runs
      const float sgn = (lr & 1) ? 1.f : -1.f;
#pragma unroll
      for (int i = 0; i < 2; ++i) {
        const int tb0 = ((row0 + i*32) & (T_ - 1)) + 4*hi;
#pragma unroll
        for (int j = 0; j < 2; ++j) {
          const int cc = col0 + j*32 + lr;
          // fold softmax scale*log2(e) into Q (q region only)
          const float qsc = (col0 + j*32 < KOFF) ? 0.18033688f : 1.0f;
          const int p0 = (cc & 63) >> 1;
          const float* fct = fcT + p0*2048 + tb0;
          const float* fst = fsT + p0*2048 + tb0;
#pragma unroll
          for (int q = 0; q < 4; ++q) {
            float4 c4 = *(const float4*)(fct + 8*q);
            float4 s4 = *(const float4*)(fst + 8*q);
#pragma unroll
            for (int r = 0; r < 4; ++r) {
              float v = acc[i][j][q*4 + r];
              float other = __shfl_xor(v, 1);
              float cse = (&c4.x)[r], sse = (&s4.x)[r];
              float out = fmaf(sgn * other, sse, v * cse) * qsc;
              const int rr = row0 + i*32 + r + 8*q + 4*hi;
              ((bf16*)Cv)[(long)rr * N + cc] = (bf16)out;
            }
          }
        }
      }
    } else {
      // V region: write V^T directly (t-contiguous 4-packs)
      const int bglob = row0 >> 11;
#pragma unroll
      for (int i = 0; i < 2; ++i)
#pragma unroll
      for (int j = 0; j < 2; ++j) {
          const int vo = col0 + j*32 + lr - VOFF;
          const long vbase = (long)((bglob*KVH_ + (vo >> 6))*HD_ + (vo & 63)) * T_;
#pragma unroll
          for (int q = 0; q < 4; ++q) {
            bf16x4 pk;
#pragma unroll
            for (int r = 0; r < 4; ++r) pk[r] = (bf16)acc[i][j][q*4 + r];
            const int t = ((row0 + i*32) & (T_ - 1)) + 8*q + 4*hi;
            *(bf16x4*)&vt[vbase + t] = pk;
          }
        }
    }
  }
}

// ---------------- GQA causal flash attention ----------------
// R8 schedule (T15 finish-lag pipeline) with the ALLOCA BUG FIXED:
// R7/R8's union{u[4]; bf16x8} reinterpret compiled to a stack object ->
// 20-33MB scratch traffic (WRITE_SIZE 37MB vs 16MB; VGPR misreported 64).
// Fragments are now built via u32x4 element-insert + __builtin_bit_cast
// (pure SSA), and launch_bounds(256,3) gives the allocator 170-VGPR
// headroom so carried state cannot force a pressure spill.
// Schedule: iteration kt issues PV(kt-1) (carried pa regs, V[(kt-1)%3])
// back-to-back with QK(kt) -- 36 MFMAs, no exp2 in between -- then
// mask+exp2+T12 in-register transpose of tile kt -> pa for kt+1.
// V triple-buffered (write of V[(kt+1)%3] never touches PV's V[(kt-1)%3]);
// K double-buffered. LDS 40960B. Per-tile accumulation order unchanged ->
// bit-identical numerics (R8 passed).
// Ledger (do NOT retry): generic char* LDS hoists (+33%, R2/R3);
// V-destaging (2.5x, R5); split-barrier counted-vmcnt (+35%, R2);
// occupancy changes (null, R1/R6); union-through-memory reinterpret
// (alloca scratch, R7/R8).
__global__ __launch_bounds__(256, 3)
void attn_kernel(const bf16* __restrict__ qkvb, const bf16* __restrict__ vt,
                 bf16* __restrict__ att) {
  const int o = blockIdx.x;                 // 1024 blocks
  const int xcd = o & 7, s = o >> 3;        // s: 0..127
  const int bh = xcd * 8 + (s & 7);         // XCD-grouped: 8 bh (2 kv heads) per XCD
  const int qt = 15 - (s >> 3);             // big q-tiles dispatched first
  const int h = bh & 31, b = bh >> 5;
  const int kvh = h >> 2;
  const int tid = threadIdx.x, w = tid >> 6, l = tid & 63;
  const int ln = l & 15, g = l >> 4;

  __shared__ __align__(16) bf16 Ks[2][4096];
  __shared__ __align__(16) bf16 Vs[3][4096];

  // staging: 256 threads stage 64x64 K and V tiles via 2 gload16 each
  const int srow = tid >> 3;                // 0..31
  const int sch  = (tid & 7) ^ (srow & 7);  // row&7 == srow&7 for both halves
  const bf16* kg = qkvb + (long)(b*T_ + srow) * NQKV + KOFF + kvh*HD_ + sch*8;
  const bf16* vg = vt + (long)((b*KVH_ + kvh) * HD_ + srow) * T_ + sch*8;
  const int ldsoff = tid * 8;               // elems; +2048 for second half

  // diag-tile q position (within 64-row k-tile) per fragment
  const int qrel0 = (w & 1)*32 + ln;
  const int qrel1 = qrel0 + 16;

  bf16x8 onesf;
  {
    const bf16 ov = (ln == 0) ? (bf16)1.0f : (bf16)0.0f;
#pragma unroll
    for (int i = 0; i < 8; ++i) onesf[i] = ov;
  }

  const int qbase = qt * 128;
  const int nt = qt * 2 + 2;
  const int myNt = qt*2 + 1 + (w >> 1);   // waves 0-1: rows [0,64); 2-3: [64,128)

  const int q0 = qbase + w*32;
  const long qb0 = (long)(b*T_ + q0 + ln) * NQKV + h*HD_;
  const long qb1 = (long)(b*T_ + q0 + 16 + ln) * NQKV + h*HD_;
  bf16x8 qf0a = *(const bf16x8*)&qkvb[qb0 + g*8];
  bf16x8 qf0b = *(const bf16x8*)&qkvb[qb0 + 32 + g*8];
  bf16x8 qf1a = *(const bf16x8*)&qkvb[qb1 + g*8];
  bf16x8 qf1b = *(const bf16x8*)&qkvb[qb1 + 32 + g*8];

  f32x4 oacc0[4], oacc1[4], osum0, osum1;
#pragma unroll
  for (int d = 0; d < 4; ++d) { oacc0[d] = 0.f; oacc1[d] = 0.f; }
  osum0 = 0.f; osum1 = 0.f;

  // carried P fragments (tile kt-1), valid when kt-1 < myNt
  bf16x8 pa0a, pa0b, pa1a, pa1b;

  // prologue: stage tile 0
  gload16(kg, &Ks[0][ldsoff]);
  gload16(kg + (long)32*NQKV, &Ks[0][ldsoff + 2048]);
  gload16(vg, &Vs[0][ldsoff]);
  gload16(vg + (long)32*T_, &Vs[0][ldsoff + 2048]);
  __syncthreads();

  int vprev = 2, vcur = 0, vnext = 1;   // (kt-1)%3, kt%3, (kt+1)%3
  for (int kt = 0; kt < nt; ++kt) {
    const int kcur = kt & 1;
    if (kt + 1 < nt) {
      const int k1 = (kt + 1) * 64;
      gload16(kg + (long)k1 * NQKV,        &Ks[kcur^1][ldsoff]);
      gload16(kg + (long)(k1+32) * NQKV,   &Ks[kcur^1][ldsoff + 2048]);
      gload16(vg + k1,                     &Vs[vnext][ldsoff]);
      gload16(vg + (long)32*T_ + k1,       &Vs[vnext][ldsoff + 2048]);
    }
    const bool doPV = (kt >= 1) && (kt - 1 < myNt);
    const bool doQK = kt < myNt;

    f32x4 sv0[4], sv1[4];
    __builtin_amdgcn_s_setprio(1);
    if (doPV) {
#pragma unroll
      for (int d = 0; d < 4; ++d) {
        const int vrow = d*16 + ln, sw = vrow & 7;
        bf16x8 vf0 = *(const bf16x8*)&Vs[vprev][vrow*64 + (( g    ^ sw) << 3)];
        bf16x8 vf1 = *(const bf16x8*)&Vs[vprev][vrow*64 + (((g+4) ^ sw) << 3)];
        oacc0[d] = __builtin_amdgcn_mfma_f32_16x16x32_bf16(vf0, pa0a, oacc0[d], 0, 0, 0);
        oacc0[d] = __builtin_amdgcn_mfma_f32_16x16x32_bf16(vf1, pa0b, oacc0[d], 0, 0, 0);
        oacc1[d] = __builtin_amdgcn_mfma_f32_16x16x32_bf16(vf0, pa1a, oacc1[d], 0, 0, 0);
        oacc1[d] = __builtin_amdgcn_mfma_f32_16x16x32_bf16(vf1, pa1b, oacc1[d], 0, 0, 0);
      }
      osum0 = __builtin_amdgcn_mfma_f32_16x16x32_bf16(onesf, pa0a, osum0, 0, 0, 0);
      osum0 = __builtin_amdgcn_mfma_f32_16x16x32_bf16(onesf, pa0b, osum0, 0, 0, 0);
      osum1 = __builtin_amdgcn_mfma_f32_16x16x32_bf16(onesf, pa1a, osum1, 0, 0, 0);
      osum1 = __builtin_amdgcn_mfma_f32_16x16x32_bf16(onesf, pa1b, osum1, 0, 0, 0);
    }
    if (doQK) {
#pragma unroll
      for (int c = 0; c < 4; ++c) {
        const int krow = c*16 + ln, sw = krow & 7;
        bf16x8 kf0 = *(const bf16x8*)&Ks[kcur][krow*64 + (( g    ^ sw) << 3)];
        bf16x8 kf1 = *(const bf16x8*)&Ks[kcur][krow*64 + (((g+4) ^ sw) << 3)];
        f32x4 z0 = 0.f, z1 = 0.f;
        z0     = __builtin_amdgcn_mfma_f32_16x16x32_bf16(kf0, qf0a, z0, 0, 0, 0);
        sv0[c] = __builtin_amdgcn_mfma_f32_16x16x32_bf16(kf1, qf0b, z0, 0, 0, 0);
        z1     = __builtin_amdgcn_mfma_f32_16x16x32_bf16(kf0, qf1a, z1, 0, 0, 0);
        sv1[c] = __builtin_amdgcn_mfma_f32_16x16x32_bf16(kf1, qf1b, z1, 0, 0, 0);
      }
    }
    __builtin_amdgcn_s_setprio(0);

    if (doQK) {
      // diag peel: mask-adds only on the wave's last tile (wave-uniform branch)
      if (kt == myNt - 1) {
#pragma unroll
        for (int c = 0; c < 4; ++c)
#pragma unroll
          for (int r = 0; r < 4; ++r) {
            const int krel = c*16 + g*4 + r;
            sv0[c][r] += (krel > qrel0) ? -1e38f : 0.f;
            sv1[c][r] += (krel > qrel1) ? -1e38f : 0.f;
          }
      }
      // softmax: bare exp2 (scale pre-folded into Q)
#pragma unroll
      for (int c = 0; c < 4; ++c)
#pragma unroll
        for (int r = 0; r < 4; ++r) {
          sv0[c][r] = exp2f(sv0[c][r]);
          sv1[c][r] = exp2f(sv1[c][r]);
        }
      // T12 in-register P->PV transpose: cvt_pk + 4x4 dword transpose across
      // 16-lane groups (permlane32/16 swaps). Fragments assembled via
      // u32x4 insert + bit_cast -- NO union/memory round-trip (alloca bug).
      {
        unsigned p0,p1,p2,p3,p4,p5,p6,p7;
        asm("v_cvt_pk_bf16_f32 %0, %1, %2" : "=v"(p0) : "v"(sv0[0][0]), "v"(sv0[0][1]));
        asm("v_cvt_pk_bf16_f32 %0, %1, %2" : "=v"(p1) : "v"(sv0[0][2]), "v"(sv0[0][3]));
        asm("v_cvt_pk_bf16_f32 %0, %1, %2" : "=v"(p2) : "v"(sv0[1][0]), "v"(sv0[1][1]));
        asm("v_cvt_pk_bf16_f32 %0, %1, %2" : "=v"(p3) : "v"(sv0[1][2]), "v"(sv0[1][3]));
        asm("v_cvt_pk_bf16_f32 %0, %1, %2" : "=v"(p4) : "v"(sv0[2][0]), "v"(sv0[2][1]));
        asm("v_cvt_pk_bf16_f32 %0, %1, %2" : "=v"(p5) : "v"(sv0[2][2]), "v"(sv0[2][3]));
        asm("v_cvt_pk_bf16_f32 %0, %1, %2" : "=v"(p6) : "v"(sv0[3][0]), "v"(sv0[3][1]));
        asm("v_cvt_pk_bf16_f32 %0, %1, %2" : "=v"(p7) : "v"(sv0[3][2]), "v"(sv0[3][3]));
        asm("v_permlane32_swap_b32 %0, %1" : "+v"(p0), "+v"(p2));
        asm("v_permlane32_swap_b32 %0, %1" : "+v"(p1), "+v"(p3));
        asm("v_permlane16_swap_b32 %0, %1" : "+v"(p0), "+v"(p2));
        asm("v_permlane16_swap_b32 %0, %1" : "+v"(p1), "+v"(p3));
        asm("v_permlane32_swap_b32 %0, %1" : "+v"(p4), "+v"(p6));
        asm("v_permlane32_swap_b32 %0, %1" : "+v"(p5), "+v"(p7));
        asm("v_permlane16_swap_b32 %0, %1" : "+v"(p4), "+v"(p6));
        asm("v_permlane16_swap_b32 %0, %1" : "+v"(p5), "+v"(p7));
        u32x4 ta, tb;
        ta[0]=p0; ta[1]=p1; ta[2]=p2; ta[3]=p3;
        tb[0]=p4; tb[1]=p5; tb[2]=p6; tb[3]=p7;
        pa0a = __builtin_bit_cast(bf16x8, ta);
        pa0b = __builtin_bit_cast(bf16x8, tb);
      }
      {
        unsigned p0,p1,p2,p3,p4,p5,p6,p7;
        asm("v_cvt_pk_bf16_f32 %0, %1, %2" : "=v"(p0) : "v"(sv1[0][0]), "v"(sv1[0][1]));
        asm("v_cvt_pk_bf16_f32 %0, %1, %2" : "=v"(p1) : "v"(sv1[0][2]), "v"(sv1[0][3]));
        asm("v_cvt_pk_bf16_f32 %0, %1, %2" : "=v"(p2) : "v"(sv1[1][0]), "v"(sv1[1][1]));
        asm("v_cvt_pk_bf16_f32 %0, %1, %2" : "=v"(p3) : "v"(sv1[1][2]), "v"(sv1[1][3]));
        asm("v_cvt_pk_bf16_f32 %0, %1, %2" : "=v"(p4) : "v"(sv1[2][0]), "v"(sv1[2][1]));
        asm("v_cvt_pk_bf16_f32 %0, %1, %2" : "=v"(p5) : "v"(sv1[2][2]), "v"(sv1[2][3]));
        asm("v_cvt_pk_bf16_f32 %0, %1, %2" : "=v"(p6) : "v"(sv1[3][0]), "v"(sv1[3][1]));
        asm("v_cvt_pk_bf16_f32 %0, %1, %2" : "=v"(p7) : "v"(sv1[3][2]), "v"(sv1[3][3]));
        asm("v_permlane32_swap_b32 %0, %1" : "+v"(p0), "+v"(p2));
        asm("v_permlane32_swap_b32 %0, %1" : "+v"(p1), "+v"(p3));
        asm("v_permlane16_swap_b32 %0, %1" : "+v"(p0), "+v"(p2));
        asm("v_permlane16_swap_b32 %0, %1" : "+v"(p1), "+v"(p3));
        asm("v_permlane32_swap_b32 %0, %1" : "+v"(p4), "+v"(p6));
        asm("v_permlane32_swap_b32 %0, %1" : "+v"(p5), "+v"(p7));
        asm("v_permlane16_swap_b32 %0, %1" : "+v"(p4), "+v"(p6));
        asm("v_permlane16_swap_b32 %0, %1" : "+v"(p5), "+v"(p7));
        u32x4 ta, tb;
        ta[0]=p0; ta[1]=p1; ta[2]=p2; ta[3]=p3;
        tb[0]=p4; tb[1]=p5; tb[2]=p6; tb[3]=p7;
        pa1a = __builtin_bit_cast(bf16x8, ta);
        pa1b = __builtin_bit_cast(bf16x8, tb);
      }
    }
    __syncthreads();
    const int t = vprev; vprev = vcur; vcur = vnext; vnext = t;
  }

  // epilogue: drain PV of the last computed tile (waves with myNt == nt)
  if (nt - 1 < myNt) {
#pragma unroll
    for (int d = 0; d < 4; ++d) {
      const int vrow = d*16 + ln, sw = vrow & 7;
      bf16x8 vf0 = *(const bf16x8*)&Vs[vprev][vrow*64 + (( g    ^ sw) << 3)];
      bf16x8 vf1 = *(const bf16x8*)&Vs[vprev][vrow*64 + (((g+4) ^ sw) << 3)];
      oacc0[d] = __builtin_amdgcn_mfma_f32_16x16x32_bf16(vf0, pa0a, oacc0[d], 0, 0, 0);
      oacc0[d] = __builtin_amdgcn_mfma_f32_16x16x32_bf16(vf1, pa0b, oacc0[d], 0, 0, 0);
      oacc1[d] = __builtin_amdgcn_mfma_f32_16x16x32_bf16(vf0, pa1a, oacc1[d], 0, 0, 0);
      oacc1[d] = __builtin_amdgcn_mfma_f32_16x16x32_bf16(vf1, pa1b, oacc1[d], 0, 0, 0);
    }
    osum0 = __builtin_amdgcn_mfma_f32_16x16x32_bf16(onesf, pa0a, osum0, 0, 0, 0);
    osum0 = __builtin_amdgcn_mfma_f32_16x16x32_bf16(onesf, pa0b, osum0, 0, 0, 0);
    osum1 = __builtin_amdgcn_mfma_f32_16x16x32_bf16(onesf, pa1a, osum1, 0, 0, 0);
    osum1 = __builtin_amdgcn_mfma_f32_16x16x32_bf16(onesf, pa1b, osum1, 0, 0, 0);
  }

  {
    const float lsum = __shfl(osum0[0], ln);
    const float inv = 1.f / lsum;
    const long ob = (long)(b*T_ + q0 + ln) * DIM_ + h*HD_;
#pragma unroll
    for (int d = 0; d < 4; ++d) {
      bf16x4 ov;
#pragma unroll
      for (int r = 0; r < 4; ++r) ov[r] = (bf16)(oacc0[d][r] * inv);
      *(bf16x4*)&att[ob + d*16 + g*4] = ov;
    }
  }
  {
    const float lsum = __shfl(osum1[0], ln);
    const float inv = 1.f / lsum;
    const long ob = (long)(b*T_ + q0 + 16 + ln) * DIM_ + h*HD_;
#pragma unroll
    for (int d = 0; d < 4; ++d) {
      bf16x4 ov;
#pragma unroll
      for (int r = 0; r < 4; ++r) ov[r] = (bf16)(oacc1[d][r] * inv);
      *(bf16x4*)&att[ob + d*16 + g*4] = ov;
    }
  }
}

// ---------------- launch ----------------
extern "C" void kernel_launch(void* const* d_in, const int* in_sizes, int n_in,
                              void* d_out, int out_size, void* d_ws, size_t ws_size,
                              hipStream_t stream) {
  const float* x  = (const float*)d_in[0];
  const float* wq = (const float*)d_in[1];
  const float* wk = (const float*)d_in[2];
  const float* wv = (const float*)d_in[3];
  const float* wo = (const float*)d_in[4];
  const float* fc = (const float*)d_in[5];
  const float* fs = (const float*)d_in[6];

  char* ws = (char*)d_ws;
  bf16* xb   = (bf16*)(ws);
  bf16* wT   = (bf16*)(ws + 16777216);
  bf16* woT  = (bf16*)(ws + 29360128);
  bf16* qkvb = (bf16*)(ws + 37748736);
  bf16* vtb  = (bf16*)(ws + 62914560);
  bf16* att  = (bf16*)(ws + 67108864);
  // transposed RoPE tables live in the att region (dead until attn writes it)
  float* fcT = (float*)(ws + 67108864);
  float* fsT = fcT + 32*2048;

  dim3 tb(32, 8);
  prep_kernel<<<18560, tb, 0, stream>>>(x, wq, wk, wv, wo, fc, fs, xb, wT, woT, fcT, fsT);

  // qkv GEMM with fused RoPE (+Q pre-scale) + V^T epilogue
  gemm_bt<1><<<(BT_ROWS/128) * (NQKV/128), 256, 0, stream>>>(
      xb, wT, qkvb, BT_ROWS, NQKV, DIM_, fcT, fsT, vtb);

  attn_kernel<<<1024, 256, 0, stream>>>(qkvb, vtb, att);

  gemm_bt<0><<<(BT_ROWS/128) * (DIM_/128), 256, 0, stream>>>(
      att, woT, d_out, BT_ROWS, DIM_, DIM_, nullptr, nullptr, nullptr);
}